// Round 1
// baseline (1344.842 us; speedup 1.0000x reference)
//
#include <hip/hip_runtime.h>
#include <math.h>

#define Bb   2048
#define Mm   2048
#define Hh   64
#define Dd   64
#define Vv   128
#define Gg   32

// Each 16-lane group owns Mm/16 = 128 rows (row k of the group = global row gidx + 16*k).
// Process UN=8 rows per pipeline step, prefetching the next step's 8 rows.
#define UN   8
#define RPG  (Mm / 16)        // 128 rows per group
#define NST  (RPG / UN)       // 16 steps

static __device__ __forceinline__ float4 ld4(const float* p) {
    return *reinterpret_cast<const float4*>(p);
}

__global__ __launch_bounds__(256, 4)
void retriever_kernel(const float* __restrict__ query,
                      const float* __restrict__ memory,
                      const float* __restrict__ Wq,  const float* __restrict__ bq,
                      const float* __restrict__ Wo,  const float* __restrict__ bo,
                      const float* __restrict__ Wg1, const float* __restrict__ bg1,
                      const float* __restrict__ Wg2, const float* __restrict__ bg2,
                      const float* __restrict__ null_vec,
                      const float* __restrict__ Wc,  const float* __restrict__ bc,
                      float* __restrict__ logits_out,
                      float* __restrict__ gate_out)
{
    constexpr float L2E = 1.44269504088896340736f;

    __shared__ float q_lds[Hh];
    __shared__ float qp_lds[Dd];
    __shared__ float red_max[16];
    __shared__ float red_den[16];
    __shared__ float red_acc[16][Dd];
    __shared__ float r_lds[Dd];
    __shared__ float out_lds[Hh];
    __shared__ float M_lds;
    __shared__ float gate_lds;

    const int b    = blockIdx.x;
    const int t    = threadIdx.x;
    const int wave = t >> 6;
    const int lane = t & 63;
    const int grp  = lane >> 4;      // 16-lane group within wave
    const int l    = lane & 15;      // lane within group
    const int gidx = (wave << 2) | grp;   // 0..15: partial-state index

    // ---- stage query row ----
    if (t < Hh) q_lds[t] = query[(size_t)b * Hh + t];
    __syncthreads();

    // ---- q_proj = (query @ Wq + bq) * (1/sqrt(D)) ----
    if (t < Dd) {
        float a = bq[t];
        #pragma unroll 8
        for (int h = 0; h < Hh; ++h)
            a = fmaf(q_lds[h], Wq[h * Dd + t], a);
        qp_lds[t] = a * 0.125f;   // fold 1/sqrt(64)
    }
    __syncthreads();

    const float4 qp = ld4(&qp_lds[4 * l]);

    // ---- single pass over memory[b]: 8-row-deep pipelined online softmax ----
    const float* memb = memory + (size_t)b * Mm * Dd;
    const float* p0   = memb + gidx * Dd + 4 * l;   // row k lives at p0 + k*1024 floats

    float  mx  = -1e30f;
    float  den = 0.f;
    float4 acc = make_float4(0.f, 0.f, 0.f, 0.f);

    // prologue: step 0's 8 rows
    float4 c0 = ld4(p0 + 0 * 1024);
    float4 c1 = ld4(p0 + 1 * 1024);
    float4 c2 = ld4(p0 + 2 * 1024);
    float4 c3 = ld4(p0 + 3 * 1024);
    float4 c4 = ld4(p0 + 4 * 1024);
    float4 c5 = ld4(p0 + 5 * 1024);
    float4 c6 = ld4(p0 + 6 * 1024);
    float4 c7 = ld4(p0 + 7 * 1024);

    auto step = [&](const float4& r0, const float4& r1, const float4& r2, const float4& r3,
                    const float4& r4, const float4& r5, const float4& r6, const float4& r7) {
        // per-lane partial dots (4 elems each)
        float s0 = r0.x*qp.x + r0.y*qp.y + r0.z*qp.z + r0.w*qp.w;
        float s1 = r1.x*qp.x + r1.y*qp.y + r1.z*qp.z + r1.w*qp.w;
        float s2 = r2.x*qp.x + r2.y*qp.y + r2.z*qp.z + r2.w*qp.w;
        float s3 = r3.x*qp.x + r3.y*qp.y + r3.z*qp.z + r3.w*qp.w;
        float s4 = r4.x*qp.x + r4.y*qp.y + r4.z*qp.z + r4.w*qp.w;
        float s5 = r5.x*qp.x + r5.y*qp.y + r5.z*qp.z + r5.w*qp.w;
        float s6 = r6.x*qp.x + r6.y*qp.y + r6.z*qp.z + r6.w*qp.w;
        float s7 = r7.x*qp.x + r7.y*qp.y + r7.z*qp.z + r7.w*qp.w;

        // 16-lane butterfly reduces — 8 independent chains, stages interleaved for ILP
        s0 += __shfl_xor(s0, 1); s1 += __shfl_xor(s1, 1); s2 += __shfl_xor(s2, 1); s3 += __shfl_xor(s3, 1);
        s4 += __shfl_xor(s4, 1); s5 += __shfl_xor(s5, 1); s6 += __shfl_xor(s6, 1); s7 += __shfl_xor(s7, 1);
        s0 += __shfl_xor(s0, 2); s1 += __shfl_xor(s1, 2); s2 += __shfl_xor(s2, 2); s3 += __shfl_xor(s3, 2);
        s4 += __shfl_xor(s4, 2); s5 += __shfl_xor(s5, 2); s6 += __shfl_xor(s6, 2); s7 += __shfl_xor(s7, 2);
        s0 += __shfl_xor(s0, 4); s1 += __shfl_xor(s1, 4); s2 += __shfl_xor(s2, 4); s3 += __shfl_xor(s3, 4);
        s4 += __shfl_xor(s4, 4); s5 += __shfl_xor(s5, 4); s6 += __shfl_xor(s6, 4); s7 += __shfl_xor(s7, 4);
        s0 += __shfl_xor(s0, 8); s1 += __shfl_xor(s1, 8); s2 += __shfl_xor(s2, 8); s3 += __shfl_xor(s3, 8);
        s4 += __shfl_xor(s4, 8); s5 += __shfl_xor(s5, 8); s6 += __shfl_xor(s6, 8); s7 += __shfl_xor(s7, 8);

        // batched online-softmax update: ONE rescale per 8 rows
        const float m01 = fmaxf(s0, s1), m23 = fmaxf(s2, s3);
        const float m45 = fmaxf(s4, s5), m67 = fmaxf(s6, s7);
        const float mxn = fmaxf(mx, fmaxf(fmaxf(m01, m23), fmaxf(m45, m67)));
        const float cs  = exp2f((mx - mxn) * L2E);
        const float w0  = exp2f((s0 - mxn) * L2E);
        const float w1  = exp2f((s1 - mxn) * L2E);
        const float w2  = exp2f((s2 - mxn) * L2E);
        const float w3  = exp2f((s3 - mxn) * L2E);
        const float w4  = exp2f((s4 - mxn) * L2E);
        const float w5  = exp2f((s5 - mxn) * L2E);
        const float w6  = exp2f((s6 - mxn) * L2E);
        const float w7  = exp2f((s7 - mxn) * L2E);
        mx  = mxn;
        den = fmaf(den, cs, ((w0 + w1) + (w2 + w3)) + ((w4 + w5) + (w6 + w7)));

        float tx = w0 * r0.x;
        tx = fmaf(w1, r1.x, tx); tx = fmaf(w2, r2.x, tx); tx = fmaf(w3, r3.x, tx);
        tx = fmaf(w4, r4.x, tx); tx = fmaf(w5, r5.x, tx); tx = fmaf(w6, r6.x, tx); tx = fmaf(w7, r7.x, tx);
        acc.x = fmaf(acc.x, cs, tx);

        float ty = w0 * r0.y;
        ty = fmaf(w1, r1.y, ty); ty = fmaf(w2, r2.y, ty); ty = fmaf(w3, r3.y, ty);
        ty = fmaf(w4, r4.y, ty); ty = fmaf(w5, r5.y, ty); ty = fmaf(w6, r6.y, ty); ty = fmaf(w7, r7.y, ty);
        acc.y = fmaf(acc.y, cs, ty);

        float tz = w0 * r0.z;
        tz = fmaf(w1, r1.z, tz); tz = fmaf(w2, r2.z, tz); tz = fmaf(w3, r3.z, tz);
        tz = fmaf(w4, r4.z, tz); tz = fmaf(w5, r5.z, tz); tz = fmaf(w6, r6.z, tz); tz = fmaf(w7, r7.z, tz);
        acc.z = fmaf(acc.z, cs, tz);

        float tw = w0 * r0.w;
        tw = fmaf(w1, r1.w, tw); tw = fmaf(w2, r2.w, tw); tw = fmaf(w3, r3.w, tw);
        tw = fmaf(w4, r4.w, tw); tw = fmaf(w5, r5.w, tw); tw = fmaf(w6, r6.w, tw); tw = fmaf(w7, r7.w, tw);
        acc.w = fmaf(acc.w, cs, tw);
    };

    // steady state: issue step u's 8 loads, then compute step u-1 (loads have a full step to land)
    for (int u = 1; u < NST; ++u) {
        const float* pn = p0 + u * (UN * 1024);
        float4 n0 = ld4(pn + 0 * 1024);
        float4 n1 = ld4(pn + 1 * 1024);
        float4 n2 = ld4(pn + 2 * 1024);
        float4 n3 = ld4(pn + 3 * 1024);
        float4 n4 = ld4(pn + 4 * 1024);
        float4 n5 = ld4(pn + 5 * 1024);
        float4 n6 = ld4(pn + 6 * 1024);
        float4 n7 = ld4(pn + 7 * 1024);
        step(c0, c1, c2, c3, c4, c5, c6, c7);
        c0 = n0; c1 = n1; c2 = n2; c3 = n3;
        c4 = n4; c5 = n5; c6 = n6; c7 = n7;
    }
    step(c0, c1, c2, c3, c4, c5, c6, c7);   // epilogue step (no prefetch)

    // ---- write 16 partial states to LDS ----
    if (l == 0) { red_max[gidx] = mx; red_den[gidx] = den; }
    *reinterpret_cast<float4*>(&red_acc[gidx][4 * l]) = acc;
    __syncthreads();

    // ---- combine partials; retrieved = acc_total / den_total ----
    if (t < Dd) {
        float Mx = red_max[0];
        #pragma unroll
        for (int g = 1; g < 16; ++g) Mx = fmaxf(Mx, red_max[g]);
        float dt = 0.f, a = 0.f;
        #pragma unroll
        for (int g = 0; g < 16; ++g) {
            const float sc = exp2f((red_max[g] - Mx) * L2E);
            dt = fmaf(red_den[g],    sc, dt);
            a  = fmaf(red_acc[g][t], sc, a);
        }
        r_lds[t] = a / dt;
        if (t == 0) M_lds = Mx;
    }
    __syncthreads();

    // ---- wave 0: retrieved_h = retrieved @ Wo + bo ; wave 1 lanes 0-31: gate MLP ----
    float rh = 0.f;
    if (t < Hh) {
        rh = bo[t];
        #pragma unroll 8
        for (int d = 0; d < Dd; ++d)
            rh = fmaf(r_lds[d], Wo[d * Hh + t], rh);
    } else if (t < 96) {
        const int g = t - 64;
        float a = fmaf(M_lds, Wg1[Hh * Gg + g], bg1[g]);
        #pragma unroll 8
        for (int i = 0; i < Hh; ++i)
            a = fmaf(q_lds[i], Wg1[i * Gg + g], a);
        a  = fmaxf(a, 0.f);     // relu
        rh = a * Wg2[g];        // partial of hidden @ Wg2
    }

    if (wave == 1) {
        // reduce gate partial across lanes 0..31 (lanes 32..63 hold 0)
        float gs = rh;
        gs += __shfl_xor(gs, 1);
        gs += __shfl_xor(gs, 2);
        gs += __shfl_xor(gs, 4);
        gs += __shfl_xor(gs, 8);
        gs += __shfl_xor(gs, 16);
        if (lane == 0) {
            const float x = gs + bg2[0];
            const float gate = 1.f / (1.f + exp2f(-x * L2E));
            gate_lds = gate;
            gate_out[b] = gate;
        }
    }
    __syncthreads();

    // ---- gated output ----
    if (t < Hh) {
        const float gate = gate_lds;
        out_lds[t] = gate * rh + (1.f - gate) * null_vec[t];
    }
    __syncthreads();

    // ---- logits = out @ Wc + bc ----
    if (t < Vv) {
        float lg = bc[t];
        #pragma unroll 8
        for (int h = 0; h < Hh; ++h)
            lg = fmaf(out_lds[h], Wc[h * Vv + t], lg);
        logits_out[(size_t)b * Vv + t] = lg;
    }
}

extern "C" void kernel_launch(void* const* d_in, const int* in_sizes, int n_in,
                              void* d_out, int out_size, void* d_ws, size_t ws_size,
                              hipStream_t stream) {
    const float* query    = (const float*)d_in[0];
    const float* memory   = (const float*)d_in[1];
    const float* Wq       = (const float*)d_in[2];
    const float* bq       = (const float*)d_in[3];
    const float* Wo       = (const float*)d_in[4];
    const float* bo       = (const float*)d_in[5];
    const float* Wg1      = (const float*)d_in[6];
    const float* bg1      = (const float*)d_in[7];
    const float* Wg2      = (const float*)d_in[8];
    const float* bg2      = (const float*)d_in[9];
    const float* null_vec = (const float*)d_in[10];
    const float* Wc       = (const float*)d_in[11];
    const float* bc       = (const float*)d_in[12];

    float* logits = (float*)d_out;                       // (B, V) flat
    float* gate   = (float*)d_out + (size_t)Bb * Vv;     // (B,)

    retriever_kernel<<<Bb, 256, 0, stream>>>(
        query, memory, Wq, bq, Wo, bo, Wg1, bg1, Wg2, bg2,
        null_vec, Wc, bc, logits, gate);
}